// Round 1
// 137.494 us; speedup vs baseline: 1.0351x; 1.0351x over previous
//
#include <hip/hip_runtime.h>

#define BB 16
#define NN 1024
#define LALPHA 0.2f
#define MAXD 192

// ---------------- CSR build from dense adjacency ----------------
__global__ void build_csr(const float* __restrict__ adj, int* __restrict__ deg,
                          int* __restrict__ cols) {
    __shared__ int cnt;
    int i = blockIdx.x;
    if (threadIdx.x == 0) cnt = 0;
    __syncthreads();
    for (int j = threadIdx.x; j < NN; j += blockDim.x) {
        if (adj[(size_t)i * NN + j] > 0.0f) {
            int p = atomicAdd(&cnt, 1);
            if (p < MAXD) cols[(size_t)i * MAXD + p] = j;
        }
    }
    __syncthreads();
    if (threadIdx.x == 0) deg[i] = cnt < MAXD ? cnt : MAXD;
}

// ---------------- fused GEMM + attention-score epilogue (layer 1) ----------------
// h[m,f] = sum_k concat(A0,A1)[m,k] * W[k,f]   (k = 128)
// s_src[m] = h[m,:] . avec[0:FOUT], s_dst[m] = h[m,:] . avec[FOUT:2FOUT]
template <int FOUT, int RB>
__global__ void gemm_score(const float* __restrict__ A0, const float* __restrict__ A1,
                           const float* __restrict__ W, const float* __restrict__ avec,
                           float* __restrict__ h, float* __restrict__ s_src,
                           float* __restrict__ s_dst) {
    constexpr int TFN = FOUT / 4;
    constexpr int NT = (RB / 4) * TFN;  // block size
    __shared__ float xs[RB][132];
    int t = threadIdx.x;
    int tf = t % TFN, tr = t / TFN;
    int f0 = tf * 4, r0 = tr * 4;
    int base = blockIdx.x * RB;

    for (int idx = t; idx < RB * 32; idx += NT) {
        int r = idx >> 5, c = (idx & 31) * 4;
        float4 v = (c < 64) ? *(const float4*)(A0 + (size_t)(base + r) * 64 + c)
                            : *(const float4*)(A1 + (size_t)(base + r) * 64 + (c - 64));
        xs[r][c] = v.x; xs[r][c + 1] = v.y; xs[r][c + 2] = v.z; xs[r][c + 3] = v.w;
    }
    __syncthreads();

    float acc[4][4] = {};
    for (int k = 0; k < 128; k += 4) {
        float4 xv[4], wv[4];
#pragma unroll
        for (int i = 0; i < 4; i++) xv[i] = *(const float4*)&xs[r0 + i][k];
#pragma unroll
        for (int i = 0; i < 4; i++) wv[i] = *(const float4*)(W + (size_t)(k + i) * FOUT + f0);
#pragma unroll
        for (int i = 0; i < 4; i++) {
            float xr[4] = {xv[i].x, xv[i].y, xv[i].z, xv[i].w};
#pragma unroll
            for (int kk = 0; kk < 4; kk++) {
                acc[i][0] += xr[kk] * wv[kk].x;
                acc[i][1] += xr[kk] * wv[kk].y;
                acc[i][2] += xr[kk] * wv[kk].z;
                acc[i][3] += xr[kk] * wv[kk].w;
            }
        }
    }

    float a_s[4], a_d[4];
#pragma unroll
    for (int i = 0; i < 4; i++) {
        a_s[i] = avec[f0 + i];
        a_d[i] = avec[FOUT + f0 + i];
    }
#pragma unroll
    for (int i = 0; i < 4; i++) {
        int m = base + r0 + i;
        *(float4*)(h + (size_t)m * FOUT + f0) =
            make_float4(acc[i][0], acc[i][1], acc[i][2], acc[i][3]);
        float ps = acc[i][0] * a_s[0] + acc[i][1] * a_s[1] + acc[i][2] * a_s[2] + acc[i][3] * a_s[3];
        float pd = acc[i][0] * a_d[0] + acc[i][1] * a_d[1] + acc[i][2] * a_d[2] + acc[i][3] * a_d[3];
#pragma unroll
        for (int o = TFN / 2; o >= 1; o >>= 1) {
            ps += __shfl_xor(ps, o);
            pd += __shfl_xor(pd, o);
        }
        if (tf == 0) {
            s_src[m] = ps;
            s_dst[m] = pd;
        }
    }
}

// ---------------- attn layer 1 (F=128) + sigmoid gates + fused gemm2 ----------------
// Per block (one wave, one row m=(b,i)):
//   gv = sigmoid(softmax(e_i) @ h1)          [128]
//   r = gv[:64], z = gv[64:]                 -> zbuf
//   X2 = [X_m, r*state_m]                    [128] (LDS)
//   h2_m = X2 @ W2                           [64]  -> h2
//   ssrc2/sdst2 = h2_m . a2 halves           -> scalars
__global__ __launch_bounds__(64) void attn1_fused(
    const int* __restrict__ deg, const int* __restrict__ cols,
    const float* __restrict__ h1, const float* __restrict__ s_src,
    const float* __restrict__ s_dst, const float* __restrict__ state,
    const float* __restrict__ X, const float* __restrict__ W2,
    const float* __restrict__ a2, float* __restrict__ zbuf,
    float* __restrict__ h2, float* __restrict__ ssrc2, float* __restrict__ sdst2) {
    int bi = blockIdx.x;
    int i = bi & (NN - 1);
    int b = bi >> 10;
    int lane = threadIdx.x;
    int d = deg[i];
    float ssrc = s_src[bi];
    __shared__ float w[MAXD];
    __shared__ int cl[MAXD];
    __shared__ float x2[128];
    for (int j = lane; j < d; j += 64) cl[j] = cols[(size_t)i * MAXD + j];
    __syncthreads();
    float mx = -1e30f;
    for (int j = lane; j < d; j += 64) {
        float e = ssrc + s_dst[b * NN + cl[j]];
        e = e > 0.f ? e : LALPHA * e;
        w[j] = e;
        mx = fmaxf(mx, e);
    }
#pragma unroll
    for (int o = 32; o >= 1; o >>= 1) mx = fmaxf(mx, __shfl_xor(mx, o));
    float sum = 0.f;
    for (int j = lane; j < d; j += 64) {
        float e = __expf(w[j] - mx);
        w[j] = e;
        sum += e;
    }
#pragma unroll
    for (int o = 32; o >= 1; o >>= 1) sum += __shfl_xor(sum, o);
    __syncthreads();
    float inv = 1.f / sum;

    // vectorized gather: lanes 0-31 handle neighbor j, lanes 32-63 neighbor j+1
    int half = lane >> 5, fl = lane & 31;
    const float* hb = h1 + (size_t)b * NN * 128;
    float4 acc = make_float4(0.f, 0.f, 0.f, 0.f);
    for (int j = 0; j < d; j += 2) {
        int jj = j + half;
        float wt = (jj < d) ? w[jj] : 0.f;
        int row = cl[(jj < d) ? jj : j];
        float4 v = *(const float4*)(hb + (size_t)row * 128 + fl * 4);
        acc.x += wt * v.x; acc.y += wt * v.y; acc.z += wt * v.z; acc.w += wt * v.w;
    }
    acc.x += __shfl_xor(acc.x, 32);
    acc.y += __shfl_xor(acc.y, 32);
    acc.z += __shfl_xor(acc.z, 32);
    acc.w += __shfl_xor(acc.w, 32);
    // lanes 0-31 (and dup 32-63) hold cols fl*4..fl*4+3 of att@h1

    size_t mo = (size_t)bi * 64;
    if (lane < 16) {
        // r gate: cols lane*4..+3 of gv ; x2[64+..] = r * state
        float4 st = *(const float4*)(state + mo + lane * 4);
        float4 rs;
        rs.x = st.x / (1.f + __expf(-acc.x * inv));
        rs.y = st.y / (1.f + __expf(-acc.y * inv));
        rs.z = st.z / (1.f + __expf(-acc.z * inv));
        rs.w = st.w / (1.f + __expf(-acc.w * inv));
        *(float4*)&x2[64 + lane * 4] = rs;
    } else if (lane < 32) {
        // z gate: cols 64..127
        float4 z;
        z.x = 1.f / (1.f + __expf(-acc.x * inv));
        z.y = 1.f / (1.f + __expf(-acc.y * inv));
        z.z = 1.f / (1.f + __expf(-acc.z * inv));
        z.w = 1.f / (1.f + __expf(-acc.w * inv));
        *(float4*)(zbuf + mo + (lane - 16) * 4) = z;
    } else if (lane < 48) {
        *(float4*)&x2[(lane - 32) * 4] = *(const float4*)(X + mo + (lane - 32) * 4);
    }
    __syncthreads();

    // fused gemm2 matvec: h2_m[lane] = sum_k x2[k] * W2[k][lane]
    float hacc = 0.f;
#pragma unroll 8
    for (int k = 0; k < 128; k += 4) {
        float4 xv = *(const float4*)&x2[k];
        hacc += xv.x * W2[(size_t)(k + 0) * 64 + lane];
        hacc += xv.y * W2[(size_t)(k + 1) * 64 + lane];
        hacc += xv.z * W2[(size_t)(k + 2) * 64 + lane];
        hacc += xv.w * W2[(size_t)(k + 3) * 64 + lane];
    }
    h2[mo + lane] = hacc;
    float ps = hacc * a2[lane];
    float pd = hacc * a2[64 + lane];
#pragma unroll
    for (int o = 32; o >= 1; o >>= 1) {
        ps += __shfl_xor(ps, o);
        pd += __shfl_xor(pd, o);
    }
    if (lane == 0) {
        ssrc2[bi] = ps;
        sdst2[bi] = pd;
    }
}

// ---------------- attn layer 2 (F=64) + tanh + GRU combine ----------------
__global__ __launch_bounds__(64) void attn2_kernel(
    const int* __restrict__ deg, const int* __restrict__ cols,
    const float* __restrict__ h2, const float* __restrict__ s_src,
    const float* __restrict__ s_dst, const float* __restrict__ state,
    const float* __restrict__ zbuf, float* __restrict__ out) {
    int bi = blockIdx.x;
    int i = bi & (NN - 1);
    int b = bi >> 10;
    int lane = threadIdx.x;
    int d = deg[i];
    float ssrc = s_src[bi];
    __shared__ float w[MAXD];
    __shared__ int cl[MAXD];
    for (int j = lane; j < d; j += 64) cl[j] = cols[(size_t)i * MAXD + j];
    __syncthreads();
    float mx = -1e30f;
    for (int j = lane; j < d; j += 64) {
        float e = ssrc + s_dst[b * NN + cl[j]];
        e = e > 0.f ? e : LALPHA * e;
        w[j] = e;
        mx = fmaxf(mx, e);
    }
#pragma unroll
    for (int o = 32; o >= 1; o >>= 1) mx = fmaxf(mx, __shfl_xor(mx, o));
    float sum = 0.f;
    for (int j = lane; j < d; j += 64) {
        float e = __expf(w[j] - mx);
        w[j] = e;
        sum += e;
    }
#pragma unroll
    for (int o = 32; o >= 1; o >>= 1) sum += __shfl_xor(sum, o);
    __syncthreads();
    float inv = 1.f / sum;

    // vectorized gather: 4 neighbors per iteration (16-lane groups)
    int q = lane >> 4, fl = lane & 15;
    const float* hb = h2 + (size_t)b * NN * 64;
    float4 acc = make_float4(0.f, 0.f, 0.f, 0.f);
    for (int j = 0; j < d; j += 4) {
        int jj = j + q;
        float wt = (jj < d) ? w[jj] : 0.f;
        int row = cl[(jj < d) ? jj : j];
        float4 v = *(const float4*)(hb + (size_t)row * 64 + fl * 4);
        acc.x += wt * v.x; acc.y += wt * v.y; acc.z += wt * v.z; acc.w += wt * v.w;
    }
    acc.x += __shfl_xor(acc.x, 32);
    acc.y += __shfl_xor(acc.y, 32);
    acc.z += __shfl_xor(acc.z, 32);
    acc.w += __shfl_xor(acc.w, 32);
    acc.x += __shfl_xor(acc.x, 16);
    acc.y += __shfl_xor(acc.y, 16);
    acc.z += __shfl_xor(acc.z, 16);
    acc.w += __shfl_xor(acc.w, 16);
    // lanes 0-15 hold cols fl*4..+3

    if (lane < 16) {
        size_t mo = (size_t)bi * 64;
        float4 z = *(const float4*)(zbuf + mo + lane * 4);
        float4 st = *(const float4*)(state + mo + lane * 4);
        float4 o4;
        o4.x = z.x * st.x + (1.f - z.x) * tanhf(acc.x * inv);
        o4.y = z.y * st.y + (1.f - z.y) * tanhf(acc.y * inv);
        o4.z = z.z * st.z + (1.f - z.z) * tanhf(acc.z * inv);
        o4.w = z.w * st.w + (1.f - z.w) * tanhf(acc.w * inv);
        *(float4*)(out + mo + lane * 4) = o4;
    }
}

extern "C" void kernel_launch(void* const* d_in, const int* in_sizes, int n_in,
                              void* d_out, int out_size, void* d_ws, size_t ws_size,
                              hipStream_t stream) {
    const float* X     = (const float*)d_in[0];
    const float* state = (const float*)d_in[1];
    const float* adj   = (const float*)d_in[2];
    const float* W1    = (const float*)d_in[3];
    const float* a1    = (const float*)d_in[4];
    const float* W2    = (const float*)d_in[5];
    const float* a2    = (const float*)d_in[6];
    float* out = (float*)d_out;

    char* ws = (char*)d_ws;
    size_t off = 0;
    auto alloc = [&](size_t bytes) -> void* {
        void* p = ws + off;
        off = (off + bytes + 255) & ~(size_t)255;
        return p;
    };
    int*   deg    = (int*)alloc(NN * sizeof(int));
    int*   cols   = (int*)alloc((size_t)NN * MAXD * sizeof(int));
    float* h1     = (float*)alloc((size_t)BB * NN * 128 * sizeof(float));
    float* ssrc1  = (float*)alloc((size_t)BB * NN * sizeof(float));
    float* sdst1  = (float*)alloc((size_t)BB * NN * sizeof(float));
    float* zbuf   = (float*)alloc((size_t)BB * NN * 64 * sizeof(float));
    float* h2     = (float*)alloc((size_t)BB * NN * 64 * sizeof(float));
    float* ssrc2  = (float*)alloc((size_t)BB * NN * sizeof(float));
    float* sdst2  = (float*)alloc((size_t)BB * NN * sizeof(float));

    const int M = BB * NN;  // 16384 rows

    build_csr<<<NN, 256, 0, stream>>>(adj, deg, cols);
    // FOUT=128, RB=32 -> 256 threads, grid 512
    gemm_score<128, 32><<<M / 32, 256, 0, stream>>>(X, state, W1, a1, h1, ssrc1, sdst1);
    attn1_fused<<<M, 64, 0, stream>>>(deg, cols, h1, ssrc1, sdst1, state, X, W2, a2,
                                      zbuf, h2, ssrc2, sdst2);
    attn2_kernel<<<M, 64, 0, stream>>>(deg, cols, h2, ssrc2, sdst2, state, zbuf, out);
}